// Round 15
// baseline (530.298 us; speedup 1.0000x reference)
//
#include <hip/hip_runtime.h>
#include <hip/hip_bf16.h>

#define NB 16384
#define NT 32
#define NI 27
#define NH 32
#define NG 26

typedef __attribute__((ext_vector_type(8))) short bf16x8;
typedef __attribute__((ext_vector_type(4))) float f32x4;
typedef __attribute__((ext_vector_type(4))) int   i32x4;

#define MFMA(a, b, c) __builtin_amdgcn_mfma_f32_16x16x32_bf16((a), (b), (c), 0, 0, 0)

static __device__ __forceinline__ int pack2(float lo, float hi) {
    unsigned short a = __builtin_bit_cast(unsigned short, __float2bfloat16(lo));
    unsigned short b = __builtin_bit_cast(unsigned short, __float2bfloat16(hi));
    return (int)(((unsigned)b << 16) | (unsigned)a);
}

// A-fragment builders (verified R9-R13). perm: pi(8*g4+j)=16*(j>>2)+4*g4+(j&3).
static __device__ __forceinline__ i32x4 make_wfrag(const float* __restrict__ W,
                                                   int rowlen, int nrows, int row,
                                                   int g4, int kbase, bool perm) {
    int w[4];
#pragma unroll
    for (int q = 0; q < 4; ++q) {
        int klo = perm ? (16 * (q >> 1) + 4 * g4 + ((2 * q) & 3))
                       : (kbase + 8 * g4 + 2 * q);
        int khi = klo + 1;
        float lo = (row < nrows && klo < rowlen) ? W[row * rowlen + klo] : 0.0f;
        float hi = (row < nrows && khi < rowlen) ? W[row * rowlen + khi] : 0.0f;
        w[q] = pack2(lo, hi);
    }
    i32x4 v = { w[0], w[1], w[2], w[3] };
    return v;
}

// Wih0 with layer-0 bias folded into virtual column NI (x[NI] := 1.0).
static __device__ __forceinline__ i32x4 make_wfrag_xb(const float* __restrict__ W,
                                                      const float* __restrict__ bi,
                                                      const float* __restrict__ bh,
                                                      int row, int g4) {
    int w[4];
#pragma unroll
    for (int q = 0; q < 4; ++q) {
        int klo = 8 * g4 + 2 * q;
        int khi = klo + 1;
        float lo = (klo < NI) ? W[row * NI + klo] : ((klo == NI) ? bi[row] + bh[row] : 0.0f);
        float hi = (khi < NI) ? W[row * NI + khi] : ((khi == NI) ? bi[row] + bh[row] : 0.0f);
        w[q] = pack2(lo, hi);
    }
    i32x4 v = { w[0], w[1], w[2], w[3] };
    return v;
}

// 4 batches/wave in 4 col-copies (cols b, b+4, b+8, b+12). Copy cp owns hidden
// units 16*(cp>>1) + 4*g4 + 2*(cp&1) + {0,1} -> 2 unit-acts per lane per layer.
// Join to full pi-order B-frag: word k comes from copy-k's lane via ds_bpermute.
// Weights in LDS (R13). Geometry fix vs R14: 256-thread blocks so (256,4) means
// 4 blocks/CU -> VGPR cap 128 (R14's (512,4) silently capped at 64 -> 1.7 GB
// of spill traffic). 1024 blocks x 4 waves = 4096 waves = 4/SIMD.
__global__ __launch_bounds__(256, 4)
void lstm_q4b(const float* __restrict__ X,   // [B,T,I] flat, consumed as [T,B,I]
              const float* __restrict__ Gu,  // [B,26]
              const float* __restrict__ H0, const float* __restrict__ C0,
              const float* __restrict__ Wih0, const float* __restrict__ Whh0,
              const float* __restrict__ bih0, const float* __restrict__ bhh0,
              const float* __restrict__ Wih1, const float* __restrict__ Whh1,
              const float* __restrict__ bih1, const float* __restrict__ bhh1,
              const float* __restrict__ Wfc, const float* __restrict__ bfc,
              float* __restrict__ out)
{
    __shared__ i32x4 sA0x[512], sA0h[512], sA1i[512], sA1h[512];  // [m][lane]
    __shared__ f32x4 sB1[32];    // [m][g4]
    __shared__ i32x4 sAfc[256];  // [part][m2][lane]

    const int tid  = threadIdx.x;
    const int lane = tid & 63;
    const int bl   = lane & 15;
    const int g4   = lane >> 4;
    const int k0   = 8 * g4;
    const int b4   = bl & 3;            // batch slot within wave
    const int cp   = bl >> 2;           // col-copy index 0..3
    const bool mh1 = (cp >> 1) != 0;    // owned hidden half
    const bool rh1 = (cp & 1) != 0;     // owned r-half
    const int wid  = blockIdx.x * 4 + (tid >> 6);
    const int batch = wid * 4 + b4;

    // bpermute byte-addrs: word k lives in lane 16*g4 + 4*k + b4
    const int ja0 = 4 * (16 * g4 + b4);
    const int ja1 = ja0 + 16, ja2 = ja0 + 32, ja3 = ja0 + 48;

    // ---------- one-time cooperative staging ----------
#pragma unroll 1
    for (int slot = tid; slot < 512; slot += 256) {
        int m = slot >> 6, ln = slot & 63;
        int bs = ln & 15, gs = ln >> 4;
        sA0x[slot] = make_wfrag_xb(Wih0, bih0, bhh0, 16 * m + bs, gs);
        sA0h[slot] = make_wfrag(Whh0, NH, 4 * NH, 16 * m + bs, gs, 0, true);
        sA1i[slot] = make_wfrag(Wih1, NH, 4 * NH, 16 * m + bs, gs, 0, true);
        sA1h[slot] = make_wfrag(Whh1, NH, 4 * NH, 16 * m + bs, gs, 0, true);
    }
    if (tid < 32) {
        int m = tid >> 2, q4_ = tid & 3;
        f32x4 b;
#pragma unroll
        for (int r = 0; r < 4; ++r) {
            int gr = 16 * m + 4 * q4_ + r;
            b[r] = bih1[gr] + bhh1[gr];
        }
        sB1[tid] = b;
    }
    {
        int part = tid >> 7, m2 = (tid >> 6) & 1, ln = tid & 63;
        int bs = ln & 15, gs = ln >> 4;
        sAfc[tid] = part ? make_wfrag(Wfc, NH + NG, NG, 16 * m2 + bs, gs, NH, false)
                         : make_wfrag(Wfc, NH + NG, NG, 16 * m2 + bs, gs, 0, true);
    }
    __syncthreads();   // only barrier; recurrence is barrier-free

    // ---------- state init (init aliases h0/c0; all col-copies identical) ----------
    const float* h0p = H0 + (size_t)batch * NH;
    const float* c0p = C0 + (size_t)batch * NH;
    i32x4 hv = { pack2(h0p[4 * g4],          h0p[4 * g4 + 1]),
                 pack2(h0p[4 * g4 + 2],      h0p[4 * g4 + 3]),
                 pack2(h0p[16 + 4 * g4],     h0p[16 + 4 * g4 + 1]),
                 pack2(h0p[16 + 4 * g4 + 2], h0p[16 + 4 * g4 + 3]) };
    bf16x8 h1f = __builtin_bit_cast(bf16x8, hv);
    bf16x8 h2f = h1f;
    const int u0 = (mh1 ? 16 : 0) + 4 * g4 + (rh1 ? 2 : 0);   // first owned unit
    float c1[2], c2[2], hsum[2];
#pragma unroll
    for (int r = 0; r < 2; ++r) {
        float c = c0p[u0 + r];
        c1[r] = c; c2[r] = c; hsum[r] = 0.0f;
    }

    // x prefetch (t=0); virtual col NI carries 1.0 for the folded layer-0 bias
    float xn[8];
    {
        const float* xp = X + (size_t)batch * NI;
#pragma unroll
        for (int j = 0; j < 8; ++j) {
            int k = k0 + j;
            xn[j] = (k < NI) ? xp[k] : ((k == NI) ? 1.0f : 0.0f);
        }
    }

    const f32x4 zero4 = { 0.0f, 0.0f, 0.0f, 0.0f };

#pragma unroll 1
    for (int t = 0; t < NT; ++t) {
        int xw[4];
#pragma unroll
        for (int q = 0; q < 4; ++q) xw[q] = pack2(xn[2 * q], xn[2 * q + 1]);
        i32x4 xv = { xw[0], xw[1], xw[2], xw[3] };
        bf16x8 xf = __builtin_bit_cast(bf16x8, xv);
        if (t + 1 < NT) {
            const float* xp = X + ((size_t)(t + 1) * NB + batch) * NI;
#pragma unroll
            for (int j = 0; j < 8; ++j) {
                int k = k0 + j;
                xn[j] = (k < NI) ? xp[k] : ((k == NI) ? 1.0f : 0.0f);
            }
        }

        f32x4 g[8];
        // ---------- layer 0 ----------
#pragma unroll
        for (int m = 0; m < 8; ++m)
            g[m] = MFMA(__builtin_bit_cast(bf16x8, sA0x[m * 64 + lane]), xf, zero4);
#pragma unroll
        for (int m = 0; m < 8; ++m)
            g[m] = MFMA(__builtin_bit_cast(bf16x8, sA0h[m * 64 + lane]), h1f, g[m]);
        float hn1[2];
#pragma unroll
        for (int r = 0; r < 2; ++r) {   // all indices compile-time (rule #20)
            float gi_ = mh1 ? (rh1 ? g[1][2 + r] : g[1][r]) : (rh1 ? g[0][2 + r] : g[0][r]);
            float gf_ = mh1 ? (rh1 ? g[3][2 + r] : g[3][r]) : (rh1 ? g[2][2 + r] : g[2][r]);
            float gg_ = mh1 ? (rh1 ? g[5][2 + r] : g[5][r]) : (rh1 ? g[4][2 + r] : g[4][r]);
            float go_ = mh1 ? (rh1 ? g[7][2 + r] : g[7][r]) : (rh1 ? g[6][2 + r] : g[6][r]);
            float ei = __expf(-gi_);
            float ef = __expf(-gf_);
            float eg = __expf(-2.0f * gg_);
            float eo = __expf(-go_);
            float ig = (1.0f - eg) * __builtin_amdgcn_rcpf(fmaf(ei, eg, ei) + eg + 1.0f);
            float fv = __builtin_amdgcn_rcpf(1.0f + ef);
            float c  = fmaf(fv, c1[r], ig);
            c1[r] = c;
            float ec = __expf(-2.0f * c);
            hn1[r] = (1.0f - ec) * __builtin_amdgcn_rcpf(fmaf(eo, ec, eo) + ec + 1.0f);
        }
        {
            int p = pack2(hn1[0], hn1[1]);
            i32x4 v = { __builtin_amdgcn_ds_bpermute(ja0, p),
                        __builtin_amdgcn_ds_bpermute(ja1, p),
                        __builtin_amdgcn_ds_bpermute(ja2, p),
                        __builtin_amdgcn_ds_bpermute(ja3, p) };
            h1f = __builtin_bit_cast(bf16x8, v);
        }

        // ---------- layer 1 ----------
#pragma unroll
        for (int m = 0; m < 8; ++m)
            g[m] = MFMA(__builtin_bit_cast(bf16x8, sA1i[m * 64 + lane]), h1f, sB1[m * 4 + g4]);
#pragma unroll
        for (int m = 0; m < 8; ++m)
            g[m] = MFMA(__builtin_bit_cast(bf16x8, sA1h[m * 64 + lane]), h2f, g[m]);
        float hn2[2];
#pragma unroll
        for (int r = 0; r < 2; ++r) {
            float gi_ = mh1 ? (rh1 ? g[1][2 + r] : g[1][r]) : (rh1 ? g[0][2 + r] : g[0][r]);
            float gf_ = mh1 ? (rh1 ? g[3][2 + r] : g[3][r]) : (rh1 ? g[2][2 + r] : g[2][r]);
            float gg_ = mh1 ? (rh1 ? g[5][2 + r] : g[5][r]) : (rh1 ? g[4][2 + r] : g[4][r]);
            float go_ = mh1 ? (rh1 ? g[7][2 + r] : g[7][r]) : (rh1 ? g[6][2 + r] : g[6][r]);
            float ei = __expf(-gi_);
            float ef = __expf(-gf_);
            float eg = __expf(-2.0f * gg_);
            float eo = __expf(-go_);
            float ig = (1.0f - eg) * __builtin_amdgcn_rcpf(fmaf(ei, eg, ei) + eg + 1.0f);
            float fv = __builtin_amdgcn_rcpf(1.0f + ef);
            float c  = fmaf(fv, c2[r], ig);
            c2[r] = c;
            float ec = __expf(-2.0f * c);
            float h  = (1.0f - ec) * __builtin_amdgcn_rcpf(fmaf(eo, ec, eo) + ec + 1.0f);
            hn2[r] = h;
            hsum[r] += h;
        }
        {
            int p = pack2(hn2[0], hn2[1]);
            i32x4 v = { __builtin_amdgcn_ds_bpermute(ja0, p),
                        __builtin_amdgcn_ds_bpermute(ja1, p),
                        __builtin_amdgcn_ds_bpermute(ja2, p),
                        __builtin_amdgcn_ds_bpermute(ja3, p) };
            h2f = __builtin_bit_cast(bf16x8, v);
        }
    }

    // ---------- fc head ----------
    bf16x8 hsf;
    {
        int p = pack2(hsum[0] * (1.0f / NT), hsum[1] * (1.0f / NT));
        i32x4 v = { __builtin_amdgcn_ds_bpermute(ja0, p),
                    __builtin_amdgcn_ds_bpermute(ja1, p),
                    __builtin_amdgcn_ds_bpermute(ja2, p),
                    __builtin_amdgcn_ds_bpermute(ja3, p) };
        hsf = __builtin_bit_cast(bf16x8, v);
    }

    int gw[4];
    {
        const float* gp = Gu + (size_t)batch * NG;
#pragma unroll
        for (int q = 0; q < 4; ++q) {
            int k = k0 + 2 * q;
            float lo = (k     < NG) ? gp[k]     : 0.0f;
            float hi = (k + 1 < NG) ? gp[k + 1] : 0.0f;
            gw[q] = pack2(lo, hi);
        }
    }
    i32x4 gv_ = { gw[0], gw[1], gw[2], gw[3] };
    bf16x8 guf = __builtin_bit_cast(bf16x8, gv_);

    f32x4 L[2];
#pragma unroll
    for (int m2 = 0; m2 < 2; ++m2)
        L[m2] = MFMA(__builtin_bit_cast(bf16x8, sAfc[m2 * 64 + lane]), hsf, zero4);
#pragma unroll
    for (int m2 = 0; m2 < 2; ++m2)
        L[m2] = MFMA(__builtin_bit_cast(bf16x8, sAfc[128 + m2 * 64 + lane]), guf, L[m2]);

    if (cp == 0) {   // col-copies hold identical logits; one writer per batch
#pragma unroll
        for (int m2 = 0; m2 < 2; ++m2)
#pragma unroll
            for (int r = 0; r < 4; ++r) {
                int row = 16 * m2 + 4 * g4 + r;
                if (row < NG) {
                    float v = L[m2][r] + bfc[row];
                    out[(size_t)batch * NG + row] = v;
                    out[(size_t)NB * NG + (size_t)batch * NG + row] =
                        __builtin_amdgcn_rcpf(1.0f + __expf(-v));
                }
            }
    }
}

extern "C" void kernel_launch(void* const* d_in, const int* in_sizes, int n_in,
                              void* d_out, int out_size, void* d_ws, size_t ws_size,
                              hipStream_t stream) {
    const float* X    = (const float*)d_in[0];
    const float* Gu   = (const float*)d_in[1];
    const float* H0   = (const float*)d_in[2];
    const float* C0   = (const float*)d_in[3];
    const float* Wih0 = (const float*)d_in[4];
    const float* Whh0 = (const float*)d_in[5];
    const float* bih0 = (const float*)d_in[6];
    const float* bhh0 = (const float*)d_in[7];
    const float* Wih1 = (const float*)d_in[8];
    const float* Whh1 = (const float*)d_in[9];
    const float* bih1 = (const float*)d_in[10];
    const float* bhh1 = (const float*)d_in[11];
    const float* Wfc  = (const float*)d_in[12];
    const float* bfc  = (const float*)d_in[13];
    float* out = (float*)d_out;

    // 1024 blocks x 4 waves = 4096 waves (4 batches each) -> 4 waves/SIMD
    dim3 grid(NB / 4 / 4), block(256);
    hipLaunchKernelGGL(lstm_q4b, grid, block, 0, stream,
                       X, Gu, H0, C0, Wih0, Whh0, bih0, bhh0,
                       Wih1, Whh1, bih1, bhh1, Wfc, bfc, out);
}

// Round 16
// 148.092 us; speedup vs baseline: 3.5809x; 3.5809x over previous
//
#include <hip/hip_runtime.h>
#include <hip/hip_bf16.h>

#define NB 16384
#define NT 32
#define NI 27
#define NH 32
#define NG 26

typedef __attribute__((ext_vector_type(8))) short bf16x8;
typedef __attribute__((ext_vector_type(4))) float f32x4;
typedef __attribute__((ext_vector_type(4))) int   i32x4;

#define MFMA(a, b, c) __builtin_amdgcn_mfma_f32_16x16x32_bf16((a), (b), (c), 0, 0, 0)

static __device__ __forceinline__ int pack2(float lo, float hi) {
    unsigned short a = __builtin_bit_cast(unsigned short, __float2bfloat16(lo));
    unsigned short b = __builtin_bit_cast(unsigned short, __float2bfloat16(hi));
    return (int)(((unsigned)b << 16) | (unsigned)a);
}

// A-fragment builders (verified R9-R15). perm: pi(8*g4+j)=16*(j>>2)+4*g4+(j&3).
static __device__ __forceinline__ i32x4 make_wfrag(const float* __restrict__ W,
                                                   int rowlen, int nrows, int row,
                                                   int g4, int kbase, bool perm) {
    int w[4];
#pragma unroll
    for (int q = 0; q < 4; ++q) {
        int klo = perm ? (16 * (q >> 1) + 4 * g4 + ((2 * q) & 3))
                       : (kbase + 8 * g4 + 2 * q);
        int khi = klo + 1;
        float lo = (row < nrows && klo < rowlen) ? W[row * rowlen + klo] : 0.0f;
        float hi = (row < nrows && khi < rowlen) ? W[row * rowlen + khi] : 0.0f;
        w[q] = pack2(lo, hi);
    }
    i32x4 v = { w[0], w[1], w[2], w[3] };
    return v;
}

// Wih0 with layer-0 bias folded into virtual column NI (x[NI] := 1.0).
static __device__ __forceinline__ i32x4 make_wfrag_xb(const float* __restrict__ W,
                                                      const float* __restrict__ bi,
                                                      const float* __restrict__ bh,
                                                      int row, int g4) {
    int w[4];
#pragma unroll
    for (int q = 0; q < 4; ++q) {
        int klo = 8 * g4 + 2 * q;
        int khi = klo + 1;
        float lo = (klo < NI) ? W[row * NI + klo] : ((klo == NI) ? bi[row] + bh[row] : 0.0f);
        float hi = (khi < NI) ? W[row * NI + khi] : ((khi == NI) ? bi[row] + bh[row] : 0.0f);
        w[q] = pack2(lo, hi);
    }
    i32x4 v = { w[0], w[1], w[2], w[3] };
    return v;
}

// 4 batches/wave in 4 col-copies; copy cp owns hidden units
// 16*(cp>>1) + 4*g4 + 2*(cp&1) + {0,1} -> 2 unit-acts per lane per layer.
// Join to pi-order B-frag: word k from copy-k's lane via ds_bpermute.
// Weights in LDS (R13). KEY vs R14/R15: NO min-waves launch-bounds arg —
// on gfx950's unified VGPR/AGPR file, (256,4) caps total regs at 128
// (64 arch) -> 1.8 GB spill. Natural allocation (~120, per R13) lets HW
// fit 3-4 waves/SIMD on its own; grid supplies 4096 waves = 4/SIMD.
__global__ __launch_bounds__(256)
void lstm_q4c(const float* __restrict__ X,   // [B,T,I] flat, consumed as [T,B,I]
              const float* __restrict__ Gu,  // [B,26]
              const float* __restrict__ H0, const float* __restrict__ C0,
              const float* __restrict__ Wih0, const float* __restrict__ Whh0,
              const float* __restrict__ bih0, const float* __restrict__ bhh0,
              const float* __restrict__ Wih1, const float* __restrict__ Whh1,
              const float* __restrict__ bih1, const float* __restrict__ bhh1,
              const float* __restrict__ Wfc, const float* __restrict__ bfc,
              float* __restrict__ out)
{
    __shared__ i32x4 sA0x[512], sA0h[512], sA1i[512], sA1h[512];  // [m][lane]
    __shared__ f32x4 sB1[32];    // [m][g4]
    __shared__ i32x4 sAfc[256];  // [part][m2][lane]

    const int tid  = threadIdx.x;
    const int lane = tid & 63;
    const int bl   = lane & 15;
    const int g4   = lane >> 4;
    const int k0   = 8 * g4;
    const int b4   = bl & 3;            // batch slot within wave
    const int cp   = bl >> 2;           // col-copy index 0..3
    const bool mh1 = (cp >> 1) != 0;    // owned hidden half
    const bool rh1 = (cp & 1) != 0;     // owned r-half
    const int wid  = blockIdx.x * 4 + (tid >> 6);
    const int batch = wid * 4 + b4;

    // bpermute byte-addrs: word k lives in lane 16*g4 + 4*k + b4
    const int ja0 = 4 * (16 * g4 + b4);
    const int ja1 = ja0 + 16, ja2 = ja0 + 32, ja3 = ja0 + 48;

    // ---------- one-time cooperative staging ----------
#pragma unroll 1
    for (int slot = tid; slot < 512; slot += 256) {
        int m = slot >> 6, ln = slot & 63;
        int bs = ln & 15, gs = ln >> 4;
        sA0x[slot] = make_wfrag_xb(Wih0, bih0, bhh0, 16 * m + bs, gs);
        sA0h[slot] = make_wfrag(Whh0, NH, 4 * NH, 16 * m + bs, gs, 0, true);
        sA1i[slot] = make_wfrag(Wih1, NH, 4 * NH, 16 * m + bs, gs, 0, true);
        sA1h[slot] = make_wfrag(Whh1, NH, 4 * NH, 16 * m + bs, gs, 0, true);
    }
    if (tid < 32) {
        int m = tid >> 2, q4_ = tid & 3;
        f32x4 b;
#pragma unroll
        for (int r = 0; r < 4; ++r) {
            int gr = 16 * m + 4 * q4_ + r;
            b[r] = bih1[gr] + bhh1[gr];
        }
        sB1[tid] = b;
    }
    {
        int part = tid >> 7, m2 = (tid >> 6) & 1, ln = tid & 63;
        int bs = ln & 15, gs = ln >> 4;
        sAfc[tid] = part ? make_wfrag(Wfc, NH + NG, NG, 16 * m2 + bs, gs, NH, false)
                         : make_wfrag(Wfc, NH + NG, NG, 16 * m2 + bs, gs, 0, true);
    }
    __syncthreads();   // only barrier; recurrence is barrier-free

    // ---------- state init (init aliases h0/c0; all col-copies identical) ----------
    const float* h0p = H0 + (size_t)batch * NH;
    const float* c0p = C0 + (size_t)batch * NH;
    i32x4 hv = { pack2(h0p[4 * g4],          h0p[4 * g4 + 1]),
                 pack2(h0p[4 * g4 + 2],      h0p[4 * g4 + 3]),
                 pack2(h0p[16 + 4 * g4],     h0p[16 + 4 * g4 + 1]),
                 pack2(h0p[16 + 4 * g4 + 2], h0p[16 + 4 * g4 + 3]) };
    bf16x8 h1f = __builtin_bit_cast(bf16x8, hv);
    bf16x8 h2f = h1f;
    const int u0 = (mh1 ? 16 : 0) + 4 * g4 + (rh1 ? 2 : 0);   // first owned unit
    float c1[2], c2[2], hsum[2];
#pragma unroll
    for (int r = 0; r < 2; ++r) {
        float c = c0p[u0 + r];
        c1[r] = c; c2[r] = c; hsum[r] = 0.0f;
    }

    // x prefetch (t=0); virtual col NI carries 1.0 for the folded layer-0 bias
    float xn[8];
    {
        const float* xp = X + (size_t)batch * NI;
#pragma unroll
        for (int j = 0; j < 8; ++j) {
            int k = k0 + j;
            xn[j] = (k < NI) ? xp[k] : ((k == NI) ? 1.0f : 0.0f);
        }
    }

    const f32x4 zero4 = { 0.0f, 0.0f, 0.0f, 0.0f };

#pragma unroll 1
    for (int t = 0; t < NT; ++t) {
        int xw[4];
#pragma unroll
        for (int q = 0; q < 4; ++q) xw[q] = pack2(xn[2 * q], xn[2 * q + 1]);
        i32x4 xv = { xw[0], xw[1], xw[2], xw[3] };
        bf16x8 xf = __builtin_bit_cast(bf16x8, xv);
        if (t + 1 < NT) {
            const float* xp = X + ((size_t)(t + 1) * NB + batch) * NI;
#pragma unroll
            for (int j = 0; j < 8; ++j) {
                int k = k0 + j;
                xn[j] = (k < NI) ? xp[k] : ((k == NI) ? 1.0f : 0.0f);
            }
        }

        f32x4 g[8];
        // ---------- layer 0 ----------
#pragma unroll
        for (int m = 0; m < 8; ++m)
            g[m] = MFMA(__builtin_bit_cast(bf16x8, sA0x[m * 64 + lane]), xf, zero4);
#pragma unroll
        for (int m = 0; m < 8; ++m)
            g[m] = MFMA(__builtin_bit_cast(bf16x8, sA0h[m * 64 + lane]), h1f, g[m]);
        float hn1[2];
#pragma unroll
        for (int r = 0; r < 2; ++r) {   // all indices compile-time (rule #20)
            float gi_ = mh1 ? (rh1 ? g[1][2 + r] : g[1][r]) : (rh1 ? g[0][2 + r] : g[0][r]);
            float gf_ = mh1 ? (rh1 ? g[3][2 + r] : g[3][r]) : (rh1 ? g[2][2 + r] : g[2][r]);
            float gg_ = mh1 ? (rh1 ? g[5][2 + r] : g[5][r]) : (rh1 ? g[4][2 + r] : g[4][r]);
            float go_ = mh1 ? (rh1 ? g[7][2 + r] : g[7][r]) : (rh1 ? g[6][2 + r] : g[6][r]);
            float ei = __expf(-gi_);
            float ef = __expf(-gf_);
            float eg = __expf(-2.0f * gg_);
            float eo = __expf(-go_);
            float ig = (1.0f - eg) * __builtin_amdgcn_rcpf(fmaf(ei, eg, ei) + eg + 1.0f);
            float fv = __builtin_amdgcn_rcpf(1.0f + ef);
            float c  = fmaf(fv, c1[r], ig);
            c1[r] = c;
            float ec = __expf(-2.0f * c);
            hn1[r] = (1.0f - ec) * __builtin_amdgcn_rcpf(fmaf(eo, ec, eo) + ec + 1.0f);
        }
        {
            int p = pack2(hn1[0], hn1[1]);
            i32x4 v = { __builtin_amdgcn_ds_bpermute(ja0, p),
                        __builtin_amdgcn_ds_bpermute(ja1, p),
                        __builtin_amdgcn_ds_bpermute(ja2, p),
                        __builtin_amdgcn_ds_bpermute(ja3, p) };
            h1f = __builtin_bit_cast(bf16x8, v);
        }

        // ---------- layer 1 ----------
#pragma unroll
        for (int m = 0; m < 8; ++m)
            g[m] = MFMA(__builtin_bit_cast(bf16x8, sA1i[m * 64 + lane]), h1f, sB1[m * 4 + g4]);
#pragma unroll
        for (int m = 0; m < 8; ++m)
            g[m] = MFMA(__builtin_bit_cast(bf16x8, sA1h[m * 64 + lane]), h2f, g[m]);
        float hn2[2];
#pragma unroll
        for (int r = 0; r < 2; ++r) {
            float gi_ = mh1 ? (rh1 ? g[1][2 + r] : g[1][r]) : (rh1 ? g[0][2 + r] : g[0][r]);
            float gf_ = mh1 ? (rh1 ? g[3][2 + r] : g[3][r]) : (rh1 ? g[2][2 + r] : g[2][r]);
            float gg_ = mh1 ? (rh1 ? g[5][2 + r] : g[5][r]) : (rh1 ? g[4][2 + r] : g[4][r]);
            float go_ = mh1 ? (rh1 ? g[7][2 + r] : g[7][r]) : (rh1 ? g[6][2 + r] : g[6][r]);
            float ei = __expf(-gi_);
            float ef = __expf(-gf_);
            float eg = __expf(-2.0f * gg_);
            float eo = __expf(-go_);
            float ig = (1.0f - eg) * __builtin_amdgcn_rcpf(fmaf(ei, eg, ei) + eg + 1.0f);
            float fv = __builtin_amdgcn_rcpf(1.0f + ef);
            float c  = fmaf(fv, c2[r], ig);
            c2[r] = c;
            float ec = __expf(-2.0f * c);
            float h  = (1.0f - ec) * __builtin_amdgcn_rcpf(fmaf(eo, ec, eo) + ec + 1.0f);
            hn2[r] = h;
            hsum[r] += h;
        }
        {
            int p = pack2(hn2[0], hn2[1]);
            i32x4 v = { __builtin_amdgcn_ds_bpermute(ja0, p),
                        __builtin_amdgcn_ds_bpermute(ja1, p),
                        __builtin_amdgcn_ds_bpermute(ja2, p),
                        __builtin_amdgcn_ds_bpermute(ja3, p) };
            h2f = __builtin_bit_cast(bf16x8, v);
        }
    }

    // ---------- fc head ----------
    bf16x8 hsf;
    {
        int p = pack2(hsum[0] * (1.0f / NT), hsum[1] * (1.0f / NT));
        i32x4 v = { __builtin_amdgcn_ds_bpermute(ja0, p),
                    __builtin_amdgcn_ds_bpermute(ja1, p),
                    __builtin_amdgcn_ds_bpermute(ja2, p),
                    __builtin_amdgcn_ds_bpermute(ja3, p) };
        hsf = __builtin_bit_cast(bf16x8, v);
    }

    int gw[4];
    {
        const float* gp = Gu + (size_t)batch * NG;
#pragma unroll
        for (int q = 0; q < 4; ++q) {
            int k = k0 + 2 * q;
            float lo = (k     < NG) ? gp[k]     : 0.0f;
            float hi = (k + 1 < NG) ? gp[k + 1] : 0.0f;
            gw[q] = pack2(lo, hi);
        }
    }
    i32x4 gv_ = { gw[0], gw[1], gw[2], gw[3] };
    bf16x8 guf = __builtin_bit_cast(bf16x8, gv_);

    f32x4 L[2];
#pragma unroll
    for (int m2 = 0; m2 < 2; ++m2)
        L[m2] = MFMA(__builtin_bit_cast(bf16x8, sAfc[m2 * 64 + lane]), hsf, zero4);
#pragma unroll
    for (int m2 = 0; m2 < 2; ++m2)
        L[m2] = MFMA(__builtin_bit_cast(bf16x8, sAfc[128 + m2 * 64 + lane]), guf, L[m2]);

    if (cp == 0) {   // col-copies hold identical logits; one writer per batch
#pragma unroll
        for (int m2 = 0; m2 < 2; ++m2)
#pragma unroll
            for (int r = 0; r < 4; ++r) {
                int row = 16 * m2 + 4 * g4 + r;
                if (row < NG) {
                    float v = L[m2][r] + bfc[row];
                    out[(size_t)batch * NG + row] = v;
                    out[(size_t)NB * NG + (size_t)batch * NG + row] =
                        __builtin_amdgcn_rcpf(1.0f + __expf(-v));
                }
            }
    }
}

extern "C" void kernel_launch(void* const* d_in, const int* in_sizes, int n_in,
                              void* d_out, int out_size, void* d_ws, size_t ws_size,
                              hipStream_t stream) {
    const float* X    = (const float*)d_in[0];
    const float* Gu   = (const float*)d_in[1];
    const float* H0   = (const float*)d_in[2];
    const float* C0   = (const float*)d_in[3];
    const float* Wih0 = (const float*)d_in[4];
    const float* Whh0 = (const float*)d_in[5];
    const float* bih0 = (const float*)d_in[6];
    const float* bhh0 = (const float*)d_in[7];
    const float* Wih1 = (const float*)d_in[8];
    const float* Whh1 = (const float*)d_in[9];
    const float* bih1 = (const float*)d_in[10];
    const float* bhh1 = (const float*)d_in[11];
    const float* Wfc  = (const float*)d_in[12];
    const float* bfc  = (const float*)d_in[13];
    float* out = (float*)d_out;

    // 1024 blocks x 4 waves = 4096 waves (4 batches each); natural regs ->
    // HW decides residency (expect 3-4 waves/SIMD)
    dim3 grid(NB / 4 / 4), block(256);
    hipLaunchKernelGGL(lstm_q4c, grid, block, 0, stream,
                       X, Gu, H0, C0, Wih0, Whh0, bih0, bhh0,
                       Wih1, Whh1, bih1, bhh1, Wfc, bfc, out);
}

// Round 17
// 81.482 us; speedup vs baseline: 6.5082x; 1.8175x over previous
//
#include <hip/hip_runtime.h>
#include <hip/hip_bf16.h>

#define NB 16384
#define NT 32
#define NI 27
#define NH 32
#define NG 26

typedef __attribute__((ext_vector_type(8))) short bf16x8;
typedef __attribute__((ext_vector_type(4))) float f32x4;
typedef __attribute__((ext_vector_type(4))) int   i32x4;

#define MFMA(a, b, c) __builtin_amdgcn_mfma_f32_16x16x32_bf16((a), (b), (c), 0, 0, 0)
#define SWZ_XOR8 0x201F   // BitMode: xor=8, and=0x1F -> lane <-> lane^8

static __device__ __forceinline__ int pack2(float lo, float hi) {
    unsigned short a = __builtin_bit_cast(unsigned short, __float2bfloat16(lo));
    unsigned short b = __builtin_bit_cast(unsigned short, __float2bfloat16(hi));
    return (int)(((unsigned)b << 16) | (unsigned)a);
}

// A-fragment builders (verified R9-R16). perm: pi(8*g4+j)=16*(j>>2)+4*g4+(j&3).
static __device__ __forceinline__ i32x4 make_wfrag(const float* __restrict__ W,
                                                   int rowlen, int nrows, int row,
                                                   int g4, int kbase, bool perm) {
    int w[4];
#pragma unroll
    for (int q = 0; q < 4; ++q) {
        int klo = perm ? (16 * (q >> 1) + 4 * g4 + ((2 * q) & 3))
                       : (kbase + 8 * g4 + 2 * q);
        int khi = klo + 1;
        float lo = (row < nrows && klo < rowlen) ? W[row * rowlen + klo] : 0.0f;
        float hi = (row < nrows && khi < rowlen) ? W[row * rowlen + khi] : 0.0f;
        w[q] = pack2(lo, hi);
    }
    i32x4 v = { w[0], w[1], w[2], w[3] };
    return v;
}

// Wih0 with layer-0 bias folded into virtual column NI (x[NI] := 1.0).
static __device__ __forceinline__ i32x4 make_wfrag_xb(const float* __restrict__ W,
                                                      const float* __restrict__ bi,
                                                      const float* __restrict__ bh,
                                                      int row, int g4) {
    int w[4];
#pragma unroll
    for (int q = 0; q < 4; ++q) {
        int klo = 8 * g4 + 2 * q;
        int khi = klo + 1;
        float lo = (klo < NI) ? W[row * NI + klo] : ((klo == NI) ? bi[row] + bh[row] : 0.0f);
        float hi = (khi < NI) ? W[row * NI + khi] : ((khi == NI) ? bi[row] + bh[row] : 0.0f);
        w[q] = pack2(lo, hi);
    }
    i32x4 v = { w[0], w[1], w[2], w[3] };
    return v;
}

// Own-half act (hn[r] = h[16*mh+4*g4+r]) -> full pi-order B-frag via partner
// lane (lane^8) ds_swizzle. Verified R10-R13.
static __device__ __forceinline__ bf16x8 join_bfrag(const float hn[4], bool mh1) {
    int p0 = pack2(hn[0], hn[1]);
    int p1 = pack2(hn[2], hn[3]);
    int q0 = __builtin_amdgcn_ds_swizzle(p0, SWZ_XOR8);
    int q1 = __builtin_amdgcn_ds_swizzle(p1, SWZ_XOR8);
    i32x4 v = { mh1 ? q0 : p0, mh1 ? q1 : p1, mh1 ? p0 : q0, mh1 ? p1 : q1 };
    return __builtin_bit_cast(bf16x8, v);
}

// dup2 activation for 4 owned units (verified R13): fused sigmoid/tanh algebra,
// compile-time indices + cndmask selects only (rule #20).
static __device__ __forceinline__ void act4(const f32x4 g[8], float cst[4], float hn[4],
                                            bool mh1) {
#pragma unroll
    for (int r = 0; r < 4; ++r) {
        float gi_ = mh1 ? g[1][r] : g[0][r];
        float gf_ = mh1 ? g[3][r] : g[2][r];
        float gg_ = mh1 ? g[5][r] : g[4][r];
        float go_ = mh1 ? g[7][r] : g[6][r];
        float ei = __expf(-gi_);
        float ef = __expf(-gf_);
        float eg = __expf(-2.0f * gg_);
        float eo = __expf(-go_);
        float ig = (1.0f - eg) * __builtin_amdgcn_rcpf(fmaf(ei, eg, ei) + eg + 1.0f);
        float fv = __builtin_amdgcn_rcpf(1.0f + ef);
        float c  = fmaf(fv, cst[r], ig);
        cst[r] = c;
        float ec = __expf(-2.0f * c);
        hn[r] = (1.0f - ec) * __builtin_amdgcn_rcpf(fmaf(eo, ec, eo) + ec + 1.0f);
    }
}

// R13 structure (dup2: 8 batches in 2 col-copies, LDS weights, 2 waves/SIMD)
// x TWO independent chains per wave (groups A/B), phase-interleaved so the
// in-order wave issues B while A's MFMA/trans/DS results are in flight.
// Each LDS weight fragment is read once and feeds both chains' MFMAs.
// 256 blocks x 4 waves = 1024 waves x 16 batches; 4 chains per SIMD.
__global__ __launch_bounds__(256)
void lstm_dual(const float* __restrict__ X,   // [B,T,I] flat, consumed as [T,B,I]
               const float* __restrict__ Gu,  // [B,26]
               const float* __restrict__ H0, const float* __restrict__ C0,
               const float* __restrict__ Wih0, const float* __restrict__ Whh0,
               const float* __restrict__ bih0, const float* __restrict__ bhh0,
               const float* __restrict__ Wih1, const float* __restrict__ Whh1,
               const float* __restrict__ bih1, const float* __restrict__ bhh1,
               const float* __restrict__ Wfc, const float* __restrict__ bfc,
               float* __restrict__ out)
{
    __shared__ i32x4 sA0x[512], sA0h[512], sA1i[512], sA1h[512];  // [m][lane]
    __shared__ f32x4 sB1[32];    // [m][g4]
    __shared__ i32x4 sAfc[256];  // [part][m2][lane]

    const int tid  = threadIdx.x;
    const int lane = tid & 63;
    const int bl   = lane & 15;
    const int g4   = lane >> 4;
    const int k0   = 8 * g4;
    const int wid  = blockIdx.x * 4 + (tid >> 6);
    const int batchA = wid * 16 + (bl & 7);
    const int batchB = batchA + 8;
    const bool mh1 = (bl >> 3) != 0;

    // ---------- one-time cooperative staging (R13) ----------
#pragma unroll 1
    for (int slot = tid; slot < 512; slot += 256) {
        int m = slot >> 6, ln = slot & 63;
        int bs = ln & 15, gs = ln >> 4;
        sA0x[slot] = make_wfrag_xb(Wih0, bih0, bhh0, 16 * m + bs, gs);
        sA0h[slot] = make_wfrag(Whh0, NH, 4 * NH, 16 * m + bs, gs, 0, true);
        sA1i[slot] = make_wfrag(Wih1, NH, 4 * NH, 16 * m + bs, gs, 0, true);
        sA1h[slot] = make_wfrag(Whh1, NH, 4 * NH, 16 * m + bs, gs, 0, true);
    }
    if (tid < 32) {
        int m = tid >> 2, q4_ = tid & 3;
        f32x4 b;
#pragma unroll
        for (int r = 0; r < 4; ++r) {
            int gr = 16 * m + 4 * q4_ + r;
            b[r] = bih1[gr] + bhh1[gr];
        }
        sB1[tid] = b;
    }
    {
        int part = tid >> 7, m2 = (tid >> 6) & 1, ln = tid & 63;
        int bs = ln & 15, gs = ln >> 4;
        sAfc[tid] = part ? make_wfrag(Wfc, NH + NG, NG, 16 * m2 + bs, gs, NH, false)
                         : make_wfrag(Wfc, NH + NG, NG, 16 * m2 + bs, gs, 0, true);
    }
    __syncthreads();   // only barrier; recurrence is barrier-free

    // ---------- state init (init aliases h0/c0; both col-copies identical) ----------
    const float* hA = H0 + (size_t)batchA * NH;
    const float* hB = H0 + (size_t)batchB * NH;
    const float* cA = C0 + (size_t)batchA * NH;
    const float* cB = C0 + (size_t)batchB * NH;
    i32x4 hvA = { pack2(hA[4 * g4], hA[4 * g4 + 1]), pack2(hA[4 * g4 + 2], hA[4 * g4 + 3]),
                  pack2(hA[16 + 4 * g4], hA[16 + 4 * g4 + 1]),
                  pack2(hA[16 + 4 * g4 + 2], hA[16 + 4 * g4 + 3]) };
    i32x4 hvB = { pack2(hB[4 * g4], hB[4 * g4 + 1]), pack2(hB[4 * g4 + 2], hB[4 * g4 + 3]),
                  pack2(hB[16 + 4 * g4], hB[16 + 4 * g4 + 1]),
                  pack2(hB[16 + 4 * g4 + 2], hB[16 + 4 * g4 + 3]) };
    bf16x8 h1fA = __builtin_bit_cast(bf16x8, hvA), h2fA = h1fA;
    bf16x8 h1fB = __builtin_bit_cast(bf16x8, hvB), h2fB = h1fB;
    float c1A[4], c2A[4], hsA[4], c1B[4], c2B[4], hsB[4];
#pragma unroll
    for (int r = 0; r < 4; ++r) {
        int u = (mh1 ? 16 : 0) + 4 * g4 + r;
        c1A[r] = cA[u]; c2A[r] = c1A[r]; hsA[r] = 0.0f;
        c1B[r] = cB[u]; c2B[r] = c1B[r]; hsB[r] = 0.0f;
    }

    // x prefetch (t=0); virtual col NI carries 1.0 (folded layer-0 bias)
    float xnA[8], xnB[8];
    {
        const float* xa = X + (size_t)batchA * NI;
        const float* xb = X + (size_t)batchB * NI;
#pragma unroll
        for (int j = 0; j < 8; ++j) {
            int k = k0 + j;
            xnA[j] = (k < NI) ? xa[k] : ((k == NI) ? 1.0f : 0.0f);
            xnB[j] = (k < NI) ? xb[k] : ((k == NI) ? 1.0f : 0.0f);
        }
    }

    const f32x4 zero4 = { 0.0f, 0.0f, 0.0f, 0.0f };

#pragma unroll 1
    for (int t = 0; t < NT; ++t) {
        int xwA[4], xwB[4];
#pragma unroll
        for (int q = 0; q < 4; ++q) {
            xwA[q] = pack2(xnA[2 * q], xnA[2 * q + 1]);
            xwB[q] = pack2(xnB[2 * q], xnB[2 * q + 1]);
        }
        i32x4 xvA = { xwA[0], xwA[1], xwA[2], xwA[3] };
        i32x4 xvB = { xwB[0], xwB[1], xwB[2], xwB[3] };
        bf16x8 xfA = __builtin_bit_cast(bf16x8, xvA);
        bf16x8 xfB = __builtin_bit_cast(bf16x8, xvB);
        if (t + 1 < NT) {
            const float* xa = X + ((size_t)(t + 1) * NB + batchA) * NI;
            const float* xb = X + ((size_t)(t + 1) * NB + batchB) * NI;
#pragma unroll
            for (int j = 0; j < 8; ++j) {
                int k = k0 + j;
                xnA[j] = (k < NI) ? xa[k] : ((k == NI) ? 1.0f : 0.0f);
                xnB[j] = (k < NI) ? xb[k] : ((k == NI) ? 1.0f : 0.0f);
            }
        }

        f32x4 gA[8], gB[8];
        // ---------- layer 0: each weight frag read once, feeds both chains ----------
#pragma unroll
        for (int m = 0; m < 8; ++m) {
            bf16x8 w = __builtin_bit_cast(bf16x8, sA0x[m * 64 + lane]);
            gA[m] = MFMA(w, xfA, zero4);
            gB[m] = MFMA(w, xfB, zero4);
        }
#pragma unroll
        for (int m = 0; m < 8; ++m) {
            bf16x8 w = __builtin_bit_cast(bf16x8, sA0h[m * 64 + lane]);
            gA[m] = MFMA(w, h1fA, gA[m]);
            gB[m] = MFMA(w, h1fB, gB[m]);
        }
        float hn1A[4], hn1B[4];
        act4(gA, c1A, hn1A, mh1);
        act4(gB, c1B, hn1B, mh1);
        h1fA = join_bfrag(hn1A, mh1);
        h1fB = join_bfrag(hn1B, mh1);

        // ---------- layer 1 ----------
#pragma unroll
        for (int m = 0; m < 8; ++m) {
            bf16x8 w = __builtin_bit_cast(bf16x8, sA1i[m * 64 + lane]);
            f32x4 b = sB1[m * 4 + g4];
            gA[m] = MFMA(w, h1fA, b);
            gB[m] = MFMA(w, h1fB, b);
        }
#pragma unroll
        for (int m = 0; m < 8; ++m) {
            bf16x8 w = __builtin_bit_cast(bf16x8, sA1h[m * 64 + lane]);
            gA[m] = MFMA(w, h2fA, gA[m]);
            gB[m] = MFMA(w, h2fB, gB[m]);
        }
        float hn2A[4], hn2B[4];
        act4(gA, c2A, hn2A, mh1);
        act4(gB, c2B, hn2B, mh1);
#pragma unroll
        for (int r = 0; r < 4; ++r) { hsA[r] += hn2A[r]; hsB[r] += hn2B[r]; }
        h2fA = join_bfrag(hn2A, mh1);
        h2fB = join_bfrag(hn2B, mh1);
    }

    // ---------- fc head (both chains) ----------
    float hA4[4], hB4[4];
#pragma unroll
    for (int r = 0; r < 4; ++r) { hA4[r] = hsA[r] * (1.0f / NT); hB4[r] = hsB[r] * (1.0f / NT); }
    bf16x8 hsfA = join_bfrag(hA4, mh1);
    bf16x8 hsfB = join_bfrag(hB4, mh1);

    int gwA[4], gwB[4];
    {
        const float* ga = Gu + (size_t)batchA * NG;
        const float* gb = Gu + (size_t)batchB * NG;
#pragma unroll
        for (int q = 0; q < 4; ++q) {
            int k = k0 + 2 * q;
            float loA = (k < NG) ? ga[k] : 0.0f, hiA = (k + 1 < NG) ? ga[k + 1] : 0.0f;
            float loB = (k < NG) ? gb[k] : 0.0f, hiB = (k + 1 < NG) ? gb[k + 1] : 0.0f;
            gwA[q] = pack2(loA, hiA);
            gwB[q] = pack2(loB, hiB);
        }
    }
    i32x4 gvA = { gwA[0], gwA[1], gwA[2], gwA[3] };
    i32x4 gvB = { gwB[0], gwB[1], gwB[2], gwB[3] };
    bf16x8 gufA = __builtin_bit_cast(bf16x8, gvA);
    bf16x8 gufB = __builtin_bit_cast(bf16x8, gvB);

    f32x4 LA[2], LB[2];
#pragma unroll
    for (int m2 = 0; m2 < 2; ++m2) {
        bf16x8 w = __builtin_bit_cast(bf16x8, sAfc[m2 * 64 + lane]);
        LA[m2] = MFMA(w, hsfA, zero4);
        LB[m2] = MFMA(w, hsfB, zero4);
    }
#pragma unroll
    for (int m2 = 0; m2 < 2; ++m2) {
        bf16x8 w = __builtin_bit_cast(bf16x8, sAfc[128 + m2 * 64 + lane]);
        LA[m2] = MFMA(w, gufA, LA[m2]);
        LB[m2] = MFMA(w, gufB, LB[m2]);
    }

    if (bl < 8) {   // col-copies hold identical logits; one writer per batch
#pragma unroll
        for (int m2 = 0; m2 < 2; ++m2)
#pragma unroll
            for (int r = 0; r < 4; ++r) {
                int row = 16 * m2 + 4 * g4 + r;
                if (row < NG) {
                    float vA = LA[m2][r] + bfc[row];
                    float vB = LB[m2][r] + bfc[row];
                    out[(size_t)batchA * NG + row] = vA;
                    out[(size_t)batchB * NG + row] = vB;
                    out[(size_t)NB * NG + (size_t)batchA * NG + row] =
                        __builtin_amdgcn_rcpf(1.0f + __expf(-vA));
                    out[(size_t)NB * NG + (size_t)batchB * NG + row] =
                        __builtin_amdgcn_rcpf(1.0f + __expf(-vB));
                }
            }
    }
}

extern "C" void kernel_launch(void* const* d_in, const int* in_sizes, int n_in,
                              void* d_out, int out_size, void* d_ws, size_t ws_size,
                              hipStream_t stream) {
    const float* X    = (const float*)d_in[0];
    const float* Gu   = (const float*)d_in[1];
    const float* H0   = (const float*)d_in[2];
    const float* C0   = (const float*)d_in[3];
    const float* Wih0 = (const float*)d_in[4];
    const float* Whh0 = (const float*)d_in[5];
    const float* bih0 = (const float*)d_in[6];
    const float* bhh0 = (const float*)d_in[7];
    const float* Wih1 = (const float*)d_in[8];
    const float* Whh1 = (const float*)d_in[9];
    const float* bih1 = (const float*)d_in[10];
    const float* bhh1 = (const float*)d_in[11];
    const float* Wfc  = (const float*)d_in[12];
    const float* bfc  = (const float*)d_in[13];
    float* out = (float*)d_out;

    // 256 blocks x 4 waves = 1024 waves, each running 2 independent dup2
    // chains (16 batches) -> 4 chains/SIMD at 2 waves/SIMD residency.
    dim3 grid(NB / 16 / 4), block(256);
    hipLaunchKernelGGL(lstm_dual, grid, block, 0, stream,
                       X, Gu, H0, C0, Wih0, Whh0, bih0, bhh0,
                       Wih1, Whh1, bih1, bhh1, Wfc, bfc, out);
}

// Round 18
// 80.147 us; speedup vs baseline: 6.6166x; 1.0167x over previous
//
#include <hip/hip_runtime.h>
#include <hip/hip_bf16.h>

#define NB 16384
#define NT 32
#define NI 27
#define NH 32
#define NG 26

#define L2E  1.4426950408889634f
#define NL2E2 -2.885390081777927f   // -2*log2(e)

typedef __attribute__((ext_vector_type(8))) short bf16x8;
typedef __attribute__((ext_vector_type(4))) float f32x4;
typedef __attribute__((ext_vector_type(4))) int   i32x4;

#define MFMA(a, b, c) __builtin_amdgcn_mfma_f32_16x16x32_bf16((a), (b), (c), 0, 0, 0)
#define SWZ_XOR8 0x201F   // BitMode: xor=8, and=0x1F -> lane <-> lane^8

static __device__ __forceinline__ float exp2x(float x) {
#if __has_builtin(__builtin_amdgcn_exp2f)
    return __builtin_amdgcn_exp2f(x);   // raw v_exp_f32: D = 2^S0
#else
    return __expf(x * 0.6931471805599453f);
#endif
}

static __device__ __forceinline__ int pack2(float lo, float hi) {
    unsigned short a = __builtin_bit_cast(unsigned short, __float2bfloat16(lo));
    unsigned short b = __builtin_bit_cast(unsigned short, __float2bfloat16(hi));
    return (int)(((unsigned)b << 16) | (unsigned)a);
}

// Gate-row scale: fold the exp2 conversion into the weights. Rows 64..95 are
// the g-gate (tanh -> needs e^(-2x) = 2^(-2*log2e*x)) -> 2*log2e; others log2e.
static __device__ __forceinline__ float rowscale(int row) {
    return (((row >> 5) & 3) == 2) ? 2.0f * L2E : L2E;
}

// A-fragment builders (layout verified R9-R17), now with a value scale s.
// perm: pi(8*g4+j)=16*(j>>2)+4*g4+(j&3).
static __device__ __forceinline__ i32x4 make_wfrag(const float* __restrict__ W,
                                                   int rowlen, int nrows, int row,
                                                   int g4, int kbase, bool perm, float s) {
    int w[4];
#pragma unroll
    for (int q = 0; q < 4; ++q) {
        int klo = perm ? (16 * (q >> 1) + 4 * g4 + ((2 * q) & 3))
                       : (kbase + 8 * g4 + 2 * q);
        int khi = klo + 1;
        float lo = (row < nrows && klo < rowlen) ? W[row * rowlen + klo] * s : 0.0f;
        float hi = (row < nrows && khi < rowlen) ? W[row * rowlen + khi] * s : 0.0f;
        w[q] = pack2(lo, hi);
    }
    i32x4 v = { w[0], w[1], w[2], w[3] };
    return v;
}

// Wih0 with layer-0 bias folded into virtual column NI (x[NI] := 1.0), scaled.
static __device__ __forceinline__ i32x4 make_wfrag_xb(const float* __restrict__ W,
                                                      const float* __restrict__ bi,
                                                      const float* __restrict__ bh,
                                                      int row, int g4, float s) {
    int w[4];
#pragma unroll
    for (int q = 0; q < 4; ++q) {
        int klo = 8 * g4 + 2 * q;
        int khi = klo + 1;
        float lo = (klo < NI) ? W[row * NI + klo] * s
                              : ((klo == NI) ? (bi[row] + bh[row]) * s : 0.0f);
        float hi = (khi < NI) ? W[row * NI + khi] * s
                              : ((khi == NI) ? (bi[row] + bh[row]) * s : 0.0f);
        w[q] = pack2(lo, hi);
    }
    i32x4 v = { w[0], w[1], w[2], w[3] };
    return v;
}

// Own-half act (hn[r] = h[16*mh+4*g4+r]) -> full pi-order B-frag via partner
// lane (lane^8) ds_swizzle. Verified R10-R17.
static __device__ __forceinline__ bf16x8 join_bfrag(const float hn[4], bool mh1) {
    int p0 = pack2(hn[0], hn[1]);
    int p1 = pack2(hn[2], hn[3]);
    int q0 = __builtin_amdgcn_ds_swizzle(p0, SWZ_XOR8);
    int q1 = __builtin_amdgcn_ds_swizzle(p1, SWZ_XOR8);
    i32x4 v = { mh1 ? q0 : p0, mh1 ? q1 : p1, mh1 ? p0 : q0, mh1 ? p1 : q1 };
    return __builtin_bit_cast(bf16x8, v);
}

// dup2 activation, exp2-scaled gates + single-rcp cell update:
// gates arrive pre-multiplied by log2e (g-gate by 2log2e) via the weights, so
// e^{-gate} = 2^{-g'} with no per-op scale mul. c' = [c*P + (1-eg)*Q]/(P*Q),
// P=(1+ei)(1+eg), Q=1+ef  -> 5 exp2 + 2 rcp per unit (was 5 exp + 3 rcp + 5 mul).
static __device__ __forceinline__ void act4(const f32x4 g[8], float cst[4], float hn[4],
                                            bool mh1) {
#pragma unroll
    for (int r = 0; r < 4; ++r) {
        float gi_ = mh1 ? g[1][r] : g[0][r];
        float gf_ = mh1 ? g[3][r] : g[2][r];
        float gg_ = mh1 ? g[5][r] : g[4][r];
        float go_ = mh1 ? g[7][r] : g[6][r];
        float ei = exp2x(-gi_);
        float ef = exp2x(-gf_);
        float eg = exp2x(-gg_);
        float eo = exp2x(-go_);
        float P  = fmaf(ei, eg, ei) + eg + 1.0f;   // (1+ei)(1+eg)
        float Q  = 1.0f + ef;
        float c  = fmaf(cst[r], P, (1.0f - eg) * Q) * __builtin_amdgcn_rcpf(P * Q);
        cst[r] = c;
        float ec = exp2x(c * NL2E2);               // e^{-2c}
        float R  = fmaf(eo, ec, eo) + ec + 1.0f;   // (1+eo)(1+ec)
        hn[r] = (1.0f - ec) * __builtin_amdgcn_rcpf(R);
    }
}

// R13 winning structure: dup2 (8 batches x 2 col-copies), weights in LDS,
// natural launch bounds (no min-waves clamp -> no spill), 2048 waves = 2/SIMD.
__global__ __launch_bounds__(256)
void lstm_x2(const float* __restrict__ X,   // [B,T,I] flat, consumed as [T,B,I]
             const float* __restrict__ Gu,  // [B,26]
             const float* __restrict__ H0, const float* __restrict__ C0,
             const float* __restrict__ Wih0, const float* __restrict__ Whh0,
             const float* __restrict__ bih0, const float* __restrict__ bhh0,
             const float* __restrict__ Wih1, const float* __restrict__ Whh1,
             const float* __restrict__ bih1, const float* __restrict__ bhh1,
             const float* __restrict__ Wfc, const float* __restrict__ bfc,
             float* __restrict__ out)
{
    __shared__ i32x4 sA0x[512], sA0h[512], sA1i[512], sA1h[512];  // [m][lane]
    __shared__ f32x4 sB1[32];    // [m][g4], scaled layer-1 bias C-init
    __shared__ i32x4 sAfc[256];  // [part][m2][lane], UNscaled (true logits)

    const int tid  = threadIdx.x;
    const int lane = tid & 63;
    const int bl   = lane & 15;
    const int g4   = lane >> 4;
    const int k0   = 8 * g4;
    const int wid  = blockIdx.x * 4 + (tid >> 6);
    const int batch = wid * 8 + (bl & 7);
    const bool mh1 = (bl >> 3) != 0;

    // ---------- one-time cooperative staging (scaled) ----------
#pragma unroll 1
    for (int slot = tid; slot < 512; slot += 256) {
        int m = slot >> 6, ln = slot & 63;
        int bs = ln & 15, gs = ln >> 4;
        int row = 16 * m + bs;
        float s = rowscale(row);
        sA0x[slot] = make_wfrag_xb(Wih0, bih0, bhh0, row, gs, s);
        sA0h[slot] = make_wfrag(Whh0, NH, 4 * NH, row, gs, 0, true, s);
        sA1i[slot] = make_wfrag(Wih1, NH, 4 * NH, row, gs, 0, true, s);
        sA1h[slot] = make_wfrag(Whh1, NH, 4 * NH, row, gs, 0, true, s);
    }
    if (tid < 32) {
        int m = tid >> 2, q4_ = tid & 3;
        f32x4 b;
#pragma unroll
        for (int r = 0; r < 4; ++r) {
            int gr = 16 * m + 4 * q4_ + r;
            b[r] = (bih1[gr] + bhh1[gr]) * rowscale(gr);
        }
        sB1[tid] = b;
    }
    {
        int part = tid >> 7, m2 = (tid >> 6) & 1, ln = tid & 63;
        int bs = ln & 15, gs = ln >> 4;
        sAfc[tid] = part ? make_wfrag(Wfc, NH + NG, NG, 16 * m2 + bs, gs, NH, false, 1.0f)
                         : make_wfrag(Wfc, NH + NG, NG, 16 * m2 + bs, gs, 0, true, 1.0f);
    }
    __syncthreads();   // only barrier; recurrence below is barrier-free

    // ---------- state init (init aliases h0/c0; both col-copies identical) ----------
    const float* h0p = H0 + (size_t)batch * NH;
    const float* c0p = C0 + (size_t)batch * NH;
    i32x4 hv = { pack2(h0p[4 * g4],          h0p[4 * g4 + 1]),
                 pack2(h0p[4 * g4 + 2],      h0p[4 * g4 + 3]),
                 pack2(h0p[16 + 4 * g4],     h0p[16 + 4 * g4 + 1]),
                 pack2(h0p[16 + 4 * g4 + 2], h0p[16 + 4 * g4 + 3]) };
    bf16x8 h1f = __builtin_bit_cast(bf16x8, hv);
    bf16x8 h2f = h1f;
    float c1[4], c2[4], hsum[4];
#pragma unroll
    for (int r = 0; r < 4; ++r) {
        float c = c0p[(mh1 ? 16 : 0) + 4 * g4 + r];   // own units only
        c1[r] = c; c2[r] = c; hsum[r] = 0.0f;
    }

    // x prefetch (t=0), packed at load (reg trim); virtual col NI carries 1.0
    int xn[4];
    {
        const float* xp = X + (size_t)batch * NI;
#pragma unroll
        for (int q = 0; q < 4; ++q) {
            int klo = k0 + 2 * q, khi = klo + 1;
            float lo = (klo < NI) ? xp[klo] : ((klo == NI) ? 1.0f : 0.0f);
            float hi = (khi < NI) ? xp[khi] : ((khi == NI) ? 1.0f : 0.0f);
            xn[q] = pack2(lo, hi);
        }
    }

    const f32x4 zero4 = { 0.0f, 0.0f, 0.0f, 0.0f };

#pragma unroll 1
    for (int t = 0; t < NT; ++t) {
        i32x4 xv = { xn[0], xn[1], xn[2], xn[3] };
        bf16x8 xf = __builtin_bit_cast(bf16x8, xv);
        if (t + 1 < NT) {
            const float* xp = X + ((size_t)(t + 1) * NB + batch) * NI;
#pragma unroll
            for (int q = 0; q < 4; ++q) {
                int klo = k0 + 2 * q, khi = klo + 1;
                float lo = (klo < NI) ? xp[klo] : ((klo == NI) ? 1.0f : 0.0f);
                float hi = (khi < NI) ? xp[khi] : ((khi == NI) ? 1.0f : 0.0f);
                xn[q] = pack2(lo, hi);
            }
        }

        f32x4 g[8];
        // ---------- layer 0 (scaled weights; bias via x's 1.0 column) ----------
#pragma unroll
        for (int m = 0; m < 8; ++m)
            g[m] = MFMA(__builtin_bit_cast(bf16x8, sA0x[m * 64 + lane]), xf, zero4);
#pragma unroll
        for (int m = 0; m < 8; ++m)
            g[m] = MFMA(__builtin_bit_cast(bf16x8, sA0h[m * 64 + lane]), h1f, g[m]);
        float hn1[4];
        act4(g, c1, hn1, mh1);
        h1f = join_bfrag(hn1, mh1);

        // ---------- layer 1 ----------
#pragma unroll
        for (int m = 0; m < 8; ++m)
            g[m] = MFMA(__builtin_bit_cast(bf16x8, sA1i[m * 64 + lane]), h1f, sB1[m * 4 + g4]);
#pragma unroll
        for (int m = 0; m < 8; ++m)
            g[m] = MFMA(__builtin_bit_cast(bf16x8, sA1h[m * 64 + lane]), h2f, g[m]);
        float hn2[4];
        act4(g, c2, hn2, mh1);
#pragma unroll
        for (int r = 0; r < 4; ++r) hsum[r] += hn2[r];
        h2f = join_bfrag(hn2, mh1);
    }

    // ---------- fc head (unscaled weights -> true logits) ----------
    float hs[4];
#pragma unroll
    for (int r = 0; r < 4; ++r) hs[r] = hsum[r] * (1.0f / NT);
    bf16x8 hsf = join_bfrag(hs, mh1);

    int gw[4];
    {
        const float* gp = Gu + (size_t)batch * NG;
#pragma unroll
        for (int q = 0; q < 4; ++q) {
            int k = k0 + 2 * q;
            float lo = (k     < NG) ? gp[k]     : 0.0f;
            float hi = (k + 1 < NG) ? gp[k + 1] : 0.0f;
            gw[q] = pack2(lo, hi);
        }
    }
    i32x4 gv_ = { gw[0], gw[1], gw[2], gw[3] };
    bf16x8 guf = __builtin_bit_cast(bf16x8, gv_);

    f32x4 L[2];
#pragma unroll
    for (int m2 = 0; m2 < 2; ++m2)
        L[m2] = MFMA(__builtin_bit_cast(bf16x8, sAfc[m2 * 64 + lane]), hsf, zero4);
#pragma unroll
    for (int m2 = 0; m2 < 2; ++m2)
        L[m2] = MFMA(__builtin_bit_cast(bf16x8, sAfc[128 + m2 * 64 + lane]), guf, L[m2]);

    if (bl < 8) {   // col-copies hold identical logits; one writer per batch
#pragma unroll
        for (int m2 = 0; m2 < 2; ++m2)
#pragma unroll
            for (int r = 0; r < 4; ++r) {
                int row = 16 * m2 + 4 * g4 + r;
                if (row < NG) {
                    float v = L[m2][r] + bfc[row];
                    out[(size_t)batch * NG + row] = v;
                    out[(size_t)NB * NG + (size_t)batch * NG + row] =
                        __builtin_amdgcn_rcpf(1.0f + exp2x(-v * L2E));
                }
            }
    }
}

extern "C" void kernel_launch(void* const* d_in, const int* in_sizes, int n_in,
                              void* d_out, int out_size, void* d_ws, size_t ws_size,
                              hipStream_t stream) {
    const float* X    = (const float*)d_in[0];
    const float* Gu   = (const float*)d_in[1];
    const float* H0   = (const float*)d_in[2];
    const float* C0   = (const float*)d_in[3];
    const float* Wih0 = (const float*)d_in[4];
    const float* Whh0 = (const float*)d_in[5];
    const float* bih0 = (const float*)d_in[6];
    const float* bhh0 = (const float*)d_in[7];
    const float* Wih1 = (const float*)d_in[8];
    const float* Whh1 = (const float*)d_in[9];
    const float* bih1 = (const float*)d_in[10];
    const float* bhh1 = (const float*)d_in[11];
    const float* Wfc  = (const float*)d_in[12];
    const float* bfc  = (const float*)d_in[13];
    float* out = (float*)d_out;

    // 512 blocks x 4 waves = 2048 waves (8 batches each) -> 2 waves/SIMD
    dim3 grid(NB / 8 / 4), block(256);
    hipLaunchKernelGGL(lstm_x2, grid, block, 0, stream,
                       X, Gu, H0, C0, Wih0, Whh0, bih0, bhh0,
                       Wih1, Whh1, bih1, bhh1, Wfc, bfc, out);
}